// Round 2
// baseline (156.210 us; speedup 1.0000x reference)
//
#include <hip/hip_runtime.h>

// MSA conv2d-like QK correlation:
// out[b, i*3+j, h, w] = sum_c Q[b,c,h,w] * K[b,c,h+i-1,w+j-1]  (zero-padded)
// B=8, C=128, H=W=128, fp32.
//
// Strategy: 1 thread per output pixel, loop over C (stride H*W). Lanes map to
// consecutive w -> fully coalesced 256B wave transactions. OOB taps have a
// fully-zero C-sum (zero padding is c-independent), so we clamp BOTH row and
// column addresses to safe in-allocation positions, accumulate garbage there,
// and zero those taps in the epilogue. No masking in the hot loop, and no
// out-of-allocation reads (row clamp alone leaves k0[-1] underflowing at
// b=0,h=0,w=0 and k0[+1] overflowing at the last element — column deltas
// dm/dp fix that).

#define Bn 8
#define Cn 128
#define Hn 128
#define Wn 128
#define HWn (Hn * Wn)

__global__ __launch_bounds__(256) void msa_conv_kernel(
    const float* __restrict__ Q, const float* __restrict__ K,
    float* __restrict__ out) {
  const int w = threadIdx.x;                    // 0..127
  const int h = blockIdx.x * 2 + threadIdx.y;   // 0..127
  const int b = blockIdx.y;                     // 0..7

  const bool wm  = (w > 0), wp  = (w < Wn - 1);
  const bool hmv = (h > 0), hpv = (h < Hn - 1);

  // Clamped neighbor rows/cols: OOB -> mirror to a safe in-bounds position
  // (result masked to 0 in the epilogue).
  const int hm = hmv ? h - 1 : h + 1;
  const int hp = hpv ? h + 1 : h - 1;
  const int dm = wm ? -1 : +1;
  const int dp = wp ? +1 : -1;

  const size_t bk = (size_t)b * Cn * HWn;
  const float* q  = Q + bk + (size_t)h * Wn + w;
  const float* km = K + bk + (size_t)hm * Wn + w;
  const float* k0 = K + bk + (size_t)h  * Wn + w;
  const float* kp = K + bk + (size_t)hp * Wn + w;
  const float* kmL = km + dm; const float* kmR = km + dp;
  const float* k0L = k0 + dm; const float* k0R = k0 + dp;
  const float* kpL = kp + dm; const float* kpR = kp + dp;

  float a00 = 0.f, a01 = 0.f, a02 = 0.f;
  float a10 = 0.f, a11 = 0.f, a12 = 0.f;
  float a20 = 0.f, a21 = 0.f, a22 = 0.f;

#pragma unroll 4
  for (int c = 0; c < Cn; ++c) {
    const float qv = *q;
    const float m0 = *kmL, m1 = *km, m2 = *kmR;
    const float z0 = *k0L, z1 = *k0, z2 = *k0R;
    const float p0 = *kpL, p1 = *kp, p2 = *kpR;
    a00 += qv * m0; a01 += qv * m1; a02 += qv * m2;
    a10 += qv * z0; a11 += qv * z1; a12 += qv * z2;
    a20 += qv * p0; a21 += qv * p1; a22 += qv * p2;
    q += HWn;
    km += HWn; kmL += HWn; kmR += HWn;
    k0 += HWn; k0L += HWn; k0R += HWn;
    kp += HWn; kpL += HWn; kpR += HWn;
  }

  // Epilogue masking: any tap whose shifted position is OOB has a fully
  // zero C-sum in the reference (zero padding), so just zero it here.
  float res[9];
  res[0] = (hmv && wm) ? a00 : 0.f;
  res[1] = hmv ? a01 : 0.f;
  res[2] = (hmv && wp) ? a02 : 0.f;
  res[3] = wm ? a10 : 0.f;
  res[4] = a11;
  res[5] = wp ? a12 : 0.f;
  res[6] = (hpv && wm) ? a20 : 0.f;
  res[7] = hpv ? a21 : 0.f;
  res[8] = (hpv && wp) ? a22 : 0.f;

  float* o = out + (size_t)b * 9 * HWn + (size_t)h * Wn + w;
#pragma unroll
  for (int t = 0; t < 9; ++t) {
    *o = res[t];
    o += HWn;
  }
}

extern "C" void kernel_launch(void* const* d_in, const int* in_sizes, int n_in,
                              void* d_out, int out_size, void* d_ws,
                              size_t ws_size, hipStream_t stream) {
  const float* Q = (const float*)d_in[0];
  const float* K = (const float*)d_in[1];
  float* out = (float*)d_out;

  dim3 block(128, 2);
  dim3 grid(Hn / 2, Bn);  // 64 x 8 = 512 blocks
  msa_conv_kernel<<<grid, block, 0, stream>>>(Q, K, out);
}